// Round 1
// baseline (1830.047 us; speedup 1.0000x reference)
//
#include <hip/hip_runtime.h>
#include <hip/hip_bf16.h>

// SharedMoE: T=8192 tokens, D=1024, F=4096, E=8 experts, top-2 + shared expert.
// Sparse bucketed bf16-MFMA implementation.
//
// d_ws layout (needs ~235.5 MB):
//   xb   : x cast to bf16              [8192][1024]        16,777,216 B
//   w1t  : W1^T bf16, 9 experts        [9][4096][1024]     75,497,472 B   (slot 8 = shared)
//   w2t  : W2^T bf16, 9 experts        [9][1024][4096]     75,497,472 B
//   h    : intermediate bf16           [8192][4096]        67,108,864 B   (reused per expert)
//   tok_list / tok_w / counts          ~0.5 MB

#define T_TOKENS 8192
#define DIM      1024
#define INTER    4096
#define NEXP     8

typedef short bf16x8 __attribute__((ext_vector_type(8)));
typedef float f32x4  __attribute__((ext_vector_type(4)));

__device__ __forceinline__ unsigned short f2b(float f) {
  union { float f; unsigned int u; } v; v.f = f;
  unsigned int u = v.u;
  return (unsigned short)((u + 0x7FFFu + ((u >> 16) & 1u)) >> 16);  // RNE
}

__global__ void init_counts_kernel(int* counts) {
  if (threadIdx.x < NEXP) counts[threadIdx.x] = 0;
}

__global__ void cast_x_kernel(const float* __restrict__ x, unsigned short* __restrict__ xb) {
  size_t i = ((size_t)blockIdx.x * 256 + threadIdx.x) * 4;
  float4 v = *(const float4*)(x + i);
  ushort4 o;
  o.x = f2b(v.x); o.y = f2b(v.y); o.z = f2b(v.z); o.w = f2b(v.w);
  *(ushort4*)(xb + i) = o;
}

// in: [K][N] fp32 (expert e<8 at routed + e*K*N, e==8 at shared). out: [N][K] bf16 per expert.
__global__ void transpose_cast_kernel(const float* __restrict__ routed,
                                      const float* __restrict__ shared_w,
                                      unsigned short* __restrict__ outb,
                                      int K, int N) {
  int e = blockIdx.z;
  const float* in = (e < NEXP) ? routed + (size_t)e * K * N : shared_w;
  unsigned short* out = outb + (size_t)e * K * N;
  __shared__ float tile[32][33];
  int n0 = blockIdx.x * 32, k0 = blockIdx.y * 32;
  int tid = threadIdx.x;
  int c = tid & 31, r0 = tid >> 5;
#pragma unroll
  for (int i = 0; i < 4; i++) {
    int r = r0 + i * 8;
    tile[r][c] = in[(size_t)(k0 + r) * N + n0 + c];
  }
  __syncthreads();
  int rr = tid >> 3;          // n-row within tile
  int c4 = (tid & 7) * 4;     // k group
  ushort4 o;
  o.x = f2b(tile[c4 + 0][rr]); o.y = f2b(tile[c4 + 1][rr]);
  o.z = f2b(tile[c4 + 2][rr]); o.w = f2b(tile[c4 + 3][rr]);
  *(ushort4*)(out + (size_t)(n0 + rr) * K + k0 + c4) = o;
}

// fp32 router: one wave per token. Exact top-2 (lowest index on ties, like lax.top_k),
// softmax over the two selected logits, atomic bucket scatter.
__global__ void router_kernel(const float* __restrict__ x, const float* __restrict__ rw,
                              int* __restrict__ counts, int* __restrict__ tok_list,
                              float* __restrict__ tok_w) {
  int wv = threadIdx.x >> 6, lane = threadIdx.x & 63;
  int t = blockIdx.x * 4 + wv;
  const float* xr = x + (size_t)t * DIM;
  float a[8];
#pragma unroll
  for (int e = 0; e < 8; e++) a[e] = 0.f;
#pragma unroll
  for (int i = 0; i < 16; i++) {
    int d = i * 64 + lane;
    float xv = xr[d];
    float4 r0 = *(const float4*)(rw + d * 8);
    float4 r1 = *(const float4*)(rw + d * 8 + 4);
    a[0] += xv * r0.x; a[1] += xv * r0.y; a[2] += xv * r0.z; a[3] += xv * r0.w;
    a[4] += xv * r1.x; a[5] += xv * r1.y; a[6] += xv * r1.z; a[7] += xv * r1.w;
  }
#pragma unroll
  for (int s = 32; s; s >>= 1) {
#pragma unroll
    for (int e = 0; e < 8; e++) a[e] += __shfl_down(a[e], s);
  }
  if (lane == 0) {
    int be = 0; float bv = a[0];
#pragma unroll
    for (int e = 1; e < 8; e++) if (a[e] > bv) { bv = a[e]; be = e; }
    int be2 = -1; float bv2 = -3.4e38f;
#pragma unroll
    for (int e = 0; e < 8; e++) if (e != be && a[e] > bv2) { bv2 = a[e]; be2 = e; }
    float w0 = 1.f / (1.f + __expf(bv2 - bv));
    int p0 = atomicAdd(counts + be, 1);
    tok_list[be * T_TOKENS + p0] = t; tok_w[be * T_TOKENS + p0] = w0;
    int p1 = atomicAdd(counts + be2, 1);
    tok_list[be2 * T_TOKENS + p1] = t; tok_w[be2 * T_TOKENS + p1] = 1.f - w0;
  }
}

// PHASE 1: h[m][0:4096] = relu(x_gathered[m] @ W1)   (A = xb, rows via tok_list)
// PHASE 2: out[tok[m]]  (+)= w[m] * (h[m] @ W2)      (A = h, direct rows)
// Tile: 128x128, BK=64, 256 threads = 4 waves, each wave 64x64 via 4x4 MFMA 16x16x32 bf16.
template <int PHASE>
__global__ __launch_bounds__(256) void gemm_kernel(
    const unsigned short* __restrict__ A, const unsigned short* __restrict__ Bt,
    unsigned short* __restrict__ H, float* __restrict__ Out,
    const int* __restrict__ counts, const int* __restrict__ tok_list,
    const float* __restrict__ tok_w, int expert) {
  const int Kd = (PHASE == 1) ? DIM : INTER;
  int count = (expert < NEXP) ? counts[expert] : T_TOKENS;
  int m0 = blockIdx.y * 128;
  if (m0 >= count) return;   // early-exit past this expert's bucket
  int n0 = blockIdx.x * 128;

  // +8 bf16 row padding -> 144B row stride: frag ds_read_b128 at 2-way banking (free)
  __shared__ __align__(16) unsigned short As[128 * 72];
  __shared__ __align__(16) unsigned short Bs[128 * 72];

  int tid = threadIdx.x;
  int trow = tid >> 3;            // 0..31, rows trow+32*i
  int tc = (tid & 7) * 8;         // k-chunk of 8 bf16
  const unsigned short* aptr[4];
#pragma unroll
  for (int i = 0; i < 4; i++) {
    int m = m0 + trow + 32 * i;
    int src;
    if (PHASE == 1)
      src = (expert < NEXP) ? ((m < count) ? tok_list[expert * T_TOKENS + m] : 0) : m;
    else
      src = m;  // h rows are bucket-ordered already
    aptr[i] = A + (size_t)src * Kd + tc;
  }
  const unsigned short* bptr = Bt + (size_t)(n0 + trow) * Kd + tc;

  f32x4 acc[4][4];
#pragma unroll
  for (int mf = 0; mf < 4; mf++)
#pragma unroll
    for (int nf = 0; nf < 4; nf++) acc[mf][nf] = (f32x4)0.f;

  int wv = tid >> 6, lane = tid & 63;
  int m_off = (wv & 1) * 64, n_off = (wv >> 1) * 64;
  int l15 = lane & 15, q = lane >> 4;

  for (int k0 = 0; k0 < Kd; k0 += 64) {
#pragma unroll
    for (int i = 0; i < 4; i++) {
      *(bf16x8*)&As[(trow + 32 * i) * 72 + tc] = *(const bf16x8*)(aptr[i] + k0);
      *(bf16x8*)&Bs[(trow + 32 * i) * 72 + tc] = *(const bf16x8*)(bptr + (size_t)32 * i * Kd + k0);
    }
    __syncthreads();
#pragma unroll
    for (int ks = 0; ks < 2; ks++) {
      bf16x8 af[4], bfr[4];
#pragma unroll
      for (int mf = 0; mf < 4; mf++)
        af[mf] = *(bf16x8*)&As[(m_off + mf * 16 + l15) * 72 + ks * 32 + q * 8];
#pragma unroll
      for (int nf = 0; nf < 4; nf++)
        bfr[nf] = *(bf16x8*)&Bs[(n_off + nf * 16 + l15) * 72 + ks * 32 + q * 8];
#pragma unroll
      for (int mf = 0; mf < 4; mf++)
#pragma unroll
        for (int nf = 0; nf < 4; nf++)
          acc[mf][nf] = __builtin_amdgcn_mfma_f32_16x16x32_bf16(af[mf], bfr[nf], acc[mf][nf], 0, 0, 0);
    }
    __syncthreads();
  }

  // C/D layout (m89-verified): col = lane&15, row = (lane>>4)*4 + i
  if (PHASE == 1) {
#pragma unroll
    for (int mf = 0; mf < 4; mf++)
#pragma unroll
      for (int i = 0; i < 4; i++) {
        int m = m0 + m_off + mf * 16 + q * 4 + i;
        if (m < count) {
#pragma unroll
          for (int nf = 0; nf < 4; nf++) {
            int f = n0 + n_off + nf * 16 + l15;
            float v = acc[mf][nf][i];
            H[(size_t)m * INTER + f] = f2b(v > 0.f ? v : 0.f);
          }
        }
      }
  } else {
#pragma unroll
    for (int mf = 0; mf < 4; mf++)
#pragma unroll
      for (int i = 0; i < 4; i++) {
        int m = m0 + m_off + mf * 16 + q * 4 + i;
        if (m < count) {
          int tokn; float sw;
          if (expert < NEXP) { tokn = tok_list[expert * T_TOKENS + m]; sw = tok_w[expert * T_TOKENS + m]; }
          else { tokn = m; sw = 1.f; }
          float* orow = Out + (size_t)tokn * DIM;
#pragma unroll
          for (int nf = 0; nf < 4; nf++) {
            int d = n0 + n_off + nf * 16 + l15;
            float v = sw * acc[mf][nf][i];
            if (expert < NEXP) orow[d] += v;   // routed: accumulate (launch-serialized, no conflicts)
            else orow[d] = v;                  // shared: initializes out
          }
        }
      }
  }
}

extern "C" void kernel_launch(void* const* d_in, const int* in_sizes, int n_in,
                              void* d_out, int out_size, void* d_ws, size_t ws_size,
                              hipStream_t stream) {
  const float* x   = (const float*)d_in[0];
  const float* sw1 = (const float*)d_in[1];
  const float* sw2 = (const float*)d_in[2];
  const float* rw1 = (const float*)d_in[3];
  const float* rw2 = (const float*)d_in[4];
  const float* rtw = (const float*)d_in[5];
  float* out = (float*)d_out;

  char* ws = (char*)d_ws;
  unsigned short* xb  = (unsigned short*)(ws);
  unsigned short* w1t = (unsigned short*)(ws + 16777216);
  unsigned short* w2t = (unsigned short*)(ws + 92274688);
  unsigned short* h   = (unsigned short*)(ws + 167772160);
  int*   tok_list     = (int*)(ws + 234881024);
  float* tok_w        = (float*)(ws + 235143168);
  int*   counts       = (int*)(ws + 235405312);
  const size_t EXP_STRIDE = (size_t)4096 * 1024;  // elements per expert weight matrix

  init_counts_kernel<<<1, 64, 0, stream>>>(counts);
  cast_x_kernel<<<(T_TOKENS * DIM) / (256 * 4), 256, 0, stream>>>(x, xb);
  transpose_cast_kernel<<<dim3(128, 32, 9), 256, 0, stream>>>(rw1, sw1, w1t, 1024, 4096);
  transpose_cast_kernel<<<dim3(32, 128, 9), 256, 0, stream>>>(rw2, sw2, w2t, 4096, 1024);
  router_kernel<<<T_TOKENS / 4, 256, 0, stream>>>(x, rtw, counts, tok_list, tok_w);

  // Shared expert first (writes/initializes out), then routed experts accumulate.
  gemm_kernel<1><<<dim3(32, 64), 256, 0, stream>>>(xb, w1t + 8 * EXP_STRIDE, h, nullptr,
                                                   counts, tok_list, tok_w, 8);
  gemm_kernel<2><<<dim3(8, 64), 256, 0, stream>>>(h, w2t + 8 * EXP_STRIDE, nullptr, out,
                                                  counts, tok_list, tok_w, 8);
  for (int e = 0; e < 8; e++) {
    gemm_kernel<1><<<dim3(32, 64), 256, 0, stream>>>(xb, w1t + e * EXP_STRIDE, h, nullptr,
                                                     counts, tok_list, tok_w, e);
    gemm_kernel<2><<<dim3(8, 64), 256, 0, stream>>>(h, w2t + e * EXP_STRIDE, nullptr, out,
                                                    counts, tok_list, tok_w, e);
  }
}

// Round 2
// 1820.663 us; speedup vs baseline: 1.0052x; 1.0052x over previous
//
#include <hip/hip_runtime.h>
#include <hip/hip_bf16.h>

// SharedMoE: T=8192 tokens, D=1024, F=4096, E=8 experts, top-2 + shared expert.
// R2: global_load_lds (width=16) GEMM staging + atomic-free router bucketing.
//
// d_ws layout (~235.5 MB):
//   xb   : x cast to bf16              [8192][1024]        16,777,216 B
//   w1t  : W1^T bf16, 9 experts        [9][4096][1024]     75,497,472 B   (slot 8 = shared)
//   w2t  : W2^T bf16, 9 experts        [9][1024][4096]     75,497,472 B
//   h    : intermediate bf16           [8192][4096]        67,108,864 B   (reused per expert;
//          first 64 KB double as router top_idx/top_w scratch, consumed before h is written)
//   tok_list / tok_w / counts          ~0.5 MB

#define T_TOKENS 8192
#define DIM      1024
#define INTER    4096
#define NEXP     8

typedef short bf16x8 __attribute__((ext_vector_type(8)));
typedef float f32x4  __attribute__((ext_vector_type(4)));

__device__ __forceinline__ unsigned short f2b(float f) {
  union { float f; unsigned int u; } v; v.f = f;
  unsigned int u = v.u;
  return (unsigned short)((u + 0x7FFFu + ((u >> 16) & 1u)) >> 16);  // RNE
}

// async global->LDS DMA, 16B per lane; LDS dest = wave-uniform base + lane*16.
__device__ __forceinline__ void load_lds16(const unsigned short* g, unsigned short* l) {
  __builtin_amdgcn_global_load_lds(
      (const __attribute__((address_space(1))) void*)g,
      (__attribute__((address_space(3))) void*)l, 16, 0, 0);
}

__global__ void cast_x_kernel(const float* __restrict__ x, unsigned short* __restrict__ xb) {
  size_t i = ((size_t)blockIdx.x * 256 + threadIdx.x) * 4;
  float4 v = *(const float4*)(x + i);
  ushort4 o;
  o.x = f2b(v.x); o.y = f2b(v.y); o.z = f2b(v.z); o.w = f2b(v.w);
  *(ushort4*)(xb + i) = o;
}

// in: [K][N] fp32 (expert e<8 at routed + e*K*N, e==8 at shared). out: [N][K] bf16 per expert.
__global__ void transpose_cast_kernel(const float* __restrict__ routed,
                                      const float* __restrict__ shared_w,
                                      unsigned short* __restrict__ outb,
                                      int K, int N) {
  int e = blockIdx.z;
  const float* in = (e < NEXP) ? routed + (size_t)e * K * N : shared_w;
  unsigned short* out = outb + (size_t)e * K * N;
  __shared__ float tile[32][33];
  int n0 = blockIdx.x * 32, k0 = blockIdx.y * 32;
  int tid = threadIdx.x;
  int c = tid & 31, r0 = tid >> 5;
#pragma unroll
  for (int i = 0; i < 4; i++) {
    int r = r0 + i * 8;
    tile[r][c] = in[(size_t)(k0 + r) * N + n0 + c];
  }
  __syncthreads();
  int rr = tid >> 3;          // n-row within tile
  int c4 = (tid & 7) * 4;     // k group
  ushort4 o;
  o.x = f2b(tile[c4 + 0][rr]); o.y = f2b(tile[c4 + 1][rr]);
  o.z = f2b(tile[c4 + 2][rr]); o.w = f2b(tile[c4 + 3][rr]);
  *(ushort4*)(out + (size_t)(n0 + rr) * K + k0 + c4) = o;
}

// Router stage 1: fp32 logits, exact top-2 (lowest index on ties, like lax.top_k),
// softmax weight. NO global atomics — writes per-token packed result.
__global__ void router_topk_kernel(const float* __restrict__ x, const float* __restrict__ rw,
                                   int* __restrict__ top_idx, float* __restrict__ top_w) {
  int wv = threadIdx.x >> 6, lane = threadIdx.x & 63;
  int t = blockIdx.x * 4 + wv;
  const float* xr = x + (size_t)t * DIM;
  float a[8];
#pragma unroll
  for (int e = 0; e < 8; e++) a[e] = 0.f;
#pragma unroll
  for (int i = 0; i < 16; i++) {
    int d = i * 64 + lane;
    float xv = xr[d];
    float4 r0 = *(const float4*)(rw + d * 8);
    float4 r1 = *(const float4*)(rw + d * 8 + 4);
    a[0] += xv * r0.x; a[1] += xv * r0.y; a[2] += xv * r0.z; a[3] += xv * r0.w;
    a[4] += xv * r1.x; a[5] += xv * r1.y; a[6] += xv * r1.z; a[7] += xv * r1.w;
  }
#pragma unroll
  for (int s = 32; s; s >>= 1) {
#pragma unroll
    for (int e = 0; e < 8; e++) a[e] += __shfl_down(a[e], s);
  }
  if (lane == 0) {
    int be = 0; float bv = a[0];
#pragma unroll
    for (int e = 1; e < 8; e++) if (a[e] > bv) { bv = a[e]; be = e; }
    int be2 = -1; float bv2 = -3.4e38f;
#pragma unroll
    for (int e = 0; e < 8; e++) if (e != be && a[e] > bv2) { bv2 = a[e]; be2 = e; }
    float w0 = 1.f / (1.f + __expf(bv2 - bv));
    top_idx[t] = be | (be2 << 8);
    top_w[t] = w0;
  }
}

// Router stage 2: single-block bucket build. All contention is LDS-local;
// exactly 8 global count stores. Order within a bucket is irrelevant.
__global__ void bucket_kernel(const int* __restrict__ top_idx, const float* __restrict__ top_w,
                              int* __restrict__ counts, int* __restrict__ tok_list,
                              float* __restrict__ tok_w) {
  __shared__ int lcount[NEXP];
  int tid = threadIdx.x;
  if (tid < NEXP) lcount[tid] = 0;
  __syncthreads();
  for (int t = tid; t < T_TOKENS; t += 256) {
    int p = top_idx[t];
    float w0 = top_w[t];
    int e0 = p & 0xff, e1 = p >> 8;
    int s0 = atomicAdd(&lcount[e0], 1);
    tok_list[e0 * T_TOKENS + s0] = t; tok_w[e0 * T_TOKENS + s0] = w0;
    int s1 = atomicAdd(&lcount[e1], 1);
    tok_list[e1 * T_TOKENS + s1] = t; tok_w[e1 * T_TOKENS + s1] = 1.f - w0;
  }
  __syncthreads();
  if (tid < NEXP) counts[tid] = lcount[tid];
}

// PHASE 1: h[m][0:4096] = relu(x_gathered[m] @ W1)   (A = xb, rows via tok_list)
// PHASE 2: out[tok[m]]  (+)= w[m] * (h[m] @ W2)      (A = h, direct rows)
// Tile 128x128, BK=64, 4 waves x (4x4) 16x16x32 bf16 MFMA.
// Staging: global_load_lds dwordx4 — unpadded [128][64] LDS tiles (DMA lane order).
template <int PHASE>
__global__ __launch_bounds__(256) void gemm_kernel(
    const unsigned short* __restrict__ A, const unsigned short* __restrict__ Bt,
    unsigned short* __restrict__ H, float* __restrict__ Out,
    const int* __restrict__ counts, const int* __restrict__ tok_list,
    const float* __restrict__ tok_w, int expert) {
  const int Kd = (PHASE == 1) ? DIM : INTER;
  int count = (expert < NEXP) ? counts[expert] : T_TOKENS;
  int m0 = blockIdx.y * 128;
  if (m0 >= count) return;   // early-exit past this expert's bucket
  int n0 = blockIdx.x * 128;

  __shared__ __align__(16) unsigned short As[128 * 64];
  __shared__ __align__(16) unsigned short Bs[128 * 64];

  int tid = threadIdx.x;
  int wv = tid >> 6, lane = tid & 63;
  int lrow = lane >> 3;           // 0..7 : row within the 8-row DMA stripe
  int lcol = (lane & 7) * 8;      // element column (8 bf16 = 16 B)

  // Each wave stages rows [wv*32, wv*32+32) of both tiles: 4 DMA instrs each.
  const unsigned short* aG[4];
  const unsigned short* bG[4];
  unsigned short* aL[4];
  unsigned short* bL[4];
#pragma unroll
  for (int i = 0; i < 4; i++) {
    int r = wv * 32 + i * 8 + lrow;    // tile row 0..127
    int m = m0 + r;
    int src;
    if (PHASE == 1)
      src = (expert < NEXP) ? ((m < count) ? tok_list[expert * T_TOKENS + m] : 0) : m;
    else
      src = m;  // h rows are bucket-ordered already
    aG[i] = A + (size_t)src * Kd + lcol;
    bG[i] = Bt + (size_t)(n0 + r) * Kd + lcol;
    aL[i] = &As[(wv * 32 + i * 8) * 64];   // wave-uniform LDS base
    bL[i] = &Bs[(wv * 32 + i * 8) * 64];
  }

  f32x4 acc[4][4];
#pragma unroll
  for (int mf = 0; mf < 4; mf++)
#pragma unroll
    for (int nf = 0; nf < 4; nf++) acc[mf][nf] = (f32x4)0.f;

  int m_off = (wv & 1) * 64, n_off = (wv >> 1) * 64;
  int l15 = lane & 15, q = lane >> 4;

  for (int k0 = 0; k0 < Kd; k0 += 64) {
#pragma unroll
    for (int i = 0; i < 4; i++) {
      load_lds16(aG[i], aL[i]);
      load_lds16(bG[i], bL[i]);
      aG[i] += 64; bG[i] += 64;
    }
    __syncthreads();   // drains DMA (vmcnt) + orders LDS
#pragma unroll
    for (int ks = 0; ks < 2; ks++) {
      bf16x8 af[4], bfr[4];
#pragma unroll
      for (int mf = 0; mf < 4; mf++)
        af[mf] = *(bf16x8*)&As[(m_off + mf * 16 + l15) * 64 + ks * 32 + q * 8];
#pragma unroll
      for (int nf = 0; nf < 4; nf++)
        bfr[nf] = *(bf16x8*)&Bs[(n_off + nf * 16 + l15) * 64 + ks * 32 + q * 8];
#pragma unroll
      for (int mf = 0; mf < 4; mf++)
#pragma unroll
        for (int nf = 0; nf < 4; nf++)
          acc[mf][nf] = __builtin_amdgcn_mfma_f32_16x16x32_bf16(af[mf], bfr[nf], acc[mf][nf], 0, 0, 0);
    }
    __syncthreads();
  }

  // C/D layout (m89-verified): col = lane&15, row = (lane>>4)*4 + i
  if (PHASE == 1) {
#pragma unroll
    for (int mf = 0; mf < 4; mf++)
#pragma unroll
      for (int i = 0; i < 4; i++) {
        int m = m0 + m_off + mf * 16 + q * 4 + i;
        if (m < count) {
#pragma unroll
          for (int nf = 0; nf < 4; nf++) {
            int f = n0 + n_off + nf * 16 + l15;
            float v = acc[mf][nf][i];
            H[(size_t)m * INTER + f] = f2b(v > 0.f ? v : 0.f);
          }
        }
      }
  } else {
#pragma unroll
    for (int mf = 0; mf < 4; mf++)
#pragma unroll
      for (int i = 0; i < 4; i++) {
        int m = m0 + m_off + mf * 16 + q * 4 + i;
        if (m < count) {
          int tokn; float sw;
          if (expert < NEXP) { tokn = tok_list[expert * T_TOKENS + m]; sw = tok_w[expert * T_TOKENS + m]; }
          else { tokn = m; sw = 1.f; }
          float* orow = Out + (size_t)tokn * DIM;
#pragma unroll
          for (int nf = 0; nf < 4; nf++) {
            int d = n0 + n_off + nf * 16 + l15;
            float v = sw * acc[mf][nf][i];
            if (expert < NEXP) orow[d] += v;   // routed: accumulate (launch-serialized, no conflicts)
            else orow[d] = v;                  // shared: initializes out
          }
        }
      }
  }
}

extern "C" void kernel_launch(void* const* d_in, const int* in_sizes, int n_in,
                              void* d_out, int out_size, void* d_ws, size_t ws_size,
                              hipStream_t stream) {
  const float* x   = (const float*)d_in[0];
  const float* sw1 = (const float*)d_in[1];
  const float* sw2 = (const float*)d_in[2];
  const float* rw1 = (const float*)d_in[3];
  const float* rw2 = (const float*)d_in[4];
  const float* rtw = (const float*)d_in[5];
  float* out = (float*)d_out;

  char* ws = (char*)d_ws;
  unsigned short* xb  = (unsigned short*)(ws);
  unsigned short* w1t = (unsigned short*)(ws + 16777216);
  unsigned short* w2t = (unsigned short*)(ws + 92274688);
  unsigned short* h   = (unsigned short*)(ws + 167772160);
  // router scratch overlaid on head of h (consumed by bucket_kernel before h is written)
  int*   top_idx      = (int*)(ws + 167772160);
  float* top_w        = (float*)(ws + 167772160 + 32768);
  int*   tok_list     = (int*)(ws + 234881024);
  float* tok_w        = (float*)(ws + 235143168);
  int*   counts       = (int*)(ws + 235405312);
  const size_t EXP_STRIDE = (size_t)4096 * 1024;  // elements per expert weight matrix

  cast_x_kernel<<<(T_TOKENS * DIM) / (256 * 4), 256, 0, stream>>>(x, xb);
  transpose_cast_kernel<<<dim3(128, 32, 9), 256, 0, stream>>>(rw1, sw1, w1t, 1024, 4096);
  transpose_cast_kernel<<<dim3(32, 128, 9), 256, 0, stream>>>(rw2, sw2, w2t, 4096, 1024);
  router_topk_kernel<<<T_TOKENS / 4, 256, 0, stream>>>(x, rtw, top_idx, top_w);
  bucket_kernel<<<1, 256, 0, stream>>>(top_idx, top_w, counts, tok_list, tok_w);

  // Shared expert first (writes/initializes out), then routed experts accumulate.
  gemm_kernel<1><<<dim3(32, 64), 256, 0, stream>>>(xb, w1t + 8 * EXP_STRIDE, h, nullptr,
                                                   counts, tok_list, tok_w, 8);
  gemm_kernel<2><<<dim3(8, 64), 256, 0, stream>>>(h, w2t + 8 * EXP_STRIDE, nullptr, out,
                                                  counts, tok_list, tok_w, 8);
  for (int e = 0; e < 8; e++) {
    gemm_kernel<1><<<dim3(32, 64), 256, 0, stream>>>(xb, w1t + e * EXP_STRIDE, h, nullptr,
                                                     counts, tok_list, tok_w, e);
    gemm_kernel<2><<<dim3(8, 64), 256, 0, stream>>>(h, w2t + e * EXP_STRIDE, nullptr, out,
                                                    counts, tok_list, tok_w, e);
  }
}

// Round 3
// 1079.494 us; speedup vs baseline: 1.6953x; 1.6866x over previous
//
#include <hip/hip_runtime.h>
#include <hip/hip_bf16.h>

// SharedMoE: T=8192 tokens, D=1024, F=4096, E=8 experts, top-2 + shared expert.
// R3: XOR-swizzled LDS (kills 16-way frag-read bank conflicts under DMA staging)
//     + single-launch batched expert GEMMs (grid.z = 9) when ws_size permits.
//
// ws layout (BIG path, ~369.6 MB):
//   xb   0          : x bf16 [8192][1024]                16,777,216 B
//   w1t  16777216   : W1^T bf16 [9][4096][1024]          75,497,472 B (slot 8 = shared)
//   w2t  92274688   : W2^T bf16 [9][1024][4096]          75,497,472 B
//   h    167772160  : [24576][4096] bf16                201,326,592 B (routed rows at offs[e],
//                     shared rows at 16384; head 64KB doubles as router scratch)
//   tok_list/tok_w/counts/offs : ~0.5 MB
// Fallback (~235.5 MB): h is [8192][4096], per-expert serialized launches.

#define T_TOKENS 8192
#define DIM      1024
#define INTER    4096
#define NEXP     8

typedef short bf16x8 __attribute__((ext_vector_type(8)));
typedef float f32x4  __attribute__((ext_vector_type(4)));

__device__ __forceinline__ unsigned short f2b(float f) {
  union { float f; unsigned int u; } v; v.f = f;
  unsigned int u = v.u;
  return (unsigned short)((u + 0x7FFFu + ((u >> 16) & 1u)) >> 16);  // RNE
}

// async global->LDS DMA, 16B per lane; LDS dest = wave-uniform base + lane*16.
__device__ __forceinline__ void load_lds16(const unsigned short* g, unsigned short* l) {
  __builtin_amdgcn_global_load_lds(
      (const __attribute__((address_space(1))) void*)g,
      (__attribute__((address_space(3))) void*)l, 16, 0, 0);
}

__global__ void cast_x_kernel(const float* __restrict__ x, unsigned short* __restrict__ xb) {
  size_t i = ((size_t)blockIdx.x * 256 + threadIdx.x) * 4;
  float4 v = *(const float4*)(x + i);
  ushort4 o;
  o.x = f2b(v.x); o.y = f2b(v.y); o.z = f2b(v.z); o.w = f2b(v.w);
  *(ushort4*)(xb + i) = o;
}

// in: [K][N] fp32 (expert e<8 at routed + e*K*N, e==8 at shared). out: [N][K] bf16 per expert.
__global__ void transpose_cast_kernel(const float* __restrict__ routed,
                                      const float* __restrict__ shared_w,
                                      unsigned short* __restrict__ outb,
                                      int K, int N) {
  int e = blockIdx.z;
  const float* in = (e < NEXP) ? routed + (size_t)e * K * N : shared_w;
  unsigned short* out = outb + (size_t)e * K * N;
  __shared__ float tile[32][33];
  int n0 = blockIdx.x * 32, k0 = blockIdx.y * 32;
  int tid = threadIdx.x;
  int c = tid & 31, r0 = tid >> 5;
#pragma unroll
  for (int i = 0; i < 4; i++) {
    int r = r0 + i * 8;
    tile[r][c] = in[(size_t)(k0 + r) * N + n0 + c];
  }
  __syncthreads();
  int rr = tid >> 3;          // n-row within tile
  int c4 = (tid & 7) * 4;     // k group
  ushort4 o;
  o.x = f2b(tile[c4 + 0][rr]); o.y = f2b(tile[c4 + 1][rr]);
  o.z = f2b(tile[c4 + 2][rr]); o.w = f2b(tile[c4 + 3][rr]);
  *(ushort4*)(out + (size_t)(n0 + rr) * K + k0 + c4) = o;
}

// Router stage 1: fp32 logits, exact top-2 (lowest index on ties, like lax.top_k),
// softmax weight. No global atomics.
__global__ void router_topk_kernel(const float* __restrict__ x, const float* __restrict__ rw,
                                   int* __restrict__ top_idx, float* __restrict__ top_w) {
  int wv = threadIdx.x >> 6, lane = threadIdx.x & 63;
  int t = blockIdx.x * 4 + wv;
  const float* xr = x + (size_t)t * DIM;
  float a[8];
#pragma unroll
  for (int e = 0; e < 8; e++) a[e] = 0.f;
#pragma unroll
  for (int i = 0; i < 16; i++) {
    int d = i * 64 + lane;
    float xv = xr[d];
    float4 r0 = *(const float4*)(rw + d * 8);
    float4 r1 = *(const float4*)(rw + d * 8 + 4);
    a[0] += xv * r0.x; a[1] += xv * r0.y; a[2] += xv * r0.z; a[3] += xv * r0.w;
    a[4] += xv * r1.x; a[5] += xv * r1.y; a[6] += xv * r1.z; a[7] += xv * r1.w;
  }
#pragma unroll
  for (int s = 32; s; s >>= 1) {
#pragma unroll
    for (int e = 0; e < 8; e++) a[e] += __shfl_down(a[e], s);
  }
  if (lane == 0) {
    int be = 0; float bv = a[0];
#pragma unroll
    for (int e = 1; e < 8; e++) if (a[e] > bv) { bv = a[e]; be = e; }
    int be2 = -1; float bv2 = -3.4e38f;
#pragma unroll
    for (int e = 0; e < 8; e++) if (e != be && a[e] > bv2) { bv2 = a[e]; be2 = e; }
    float w0 = 1.f / (1.f + __expf(bv2 - bv));
    top_idx[t] = be | (be2 << 8);
    top_w[t] = w0;
  }
}

// Router stage 2: single-block bucket build (LDS atomics only) + prefix offsets.
__global__ void bucket_kernel(const int* __restrict__ top_idx, const float* __restrict__ top_w,
                              int* __restrict__ counts, int* __restrict__ offs,
                              int* __restrict__ tok_list, float* __restrict__ tok_w) {
  __shared__ int lcount[NEXP];
  int tid = threadIdx.x;
  if (tid < NEXP) lcount[tid] = 0;
  __syncthreads();
  for (int t = tid; t < T_TOKENS; t += 256) {
    int p = top_idx[t];
    float w0 = top_w[t];
    int e0 = p & 0xff, e1 = p >> 8;
    int s0 = atomicAdd(&lcount[e0], 1);
    tok_list[e0 * T_TOKENS + s0] = t; tok_w[e0 * T_TOKENS + s0] = w0;
    int s1 = atomicAdd(&lcount[e1], 1);
    tok_list[e1 * T_TOKENS + s1] = t; tok_w[e1 * T_TOKENS + s1] = 1.f - w0;
  }
  __syncthreads();
  if (tid == 0) {
    int run = 0;
    for (int e = 0; e < NEXP; e++) { counts[e] = lcount[e]; offs[e] = run; run += lcount[e]; }
    offs[NEXP] = run;  // == 2*T_TOKENS = 16384 always
  }
}

// PHASE 1: h[hbase+m] = relu(x_gathered[m] @ W1_e)
// PHASE 2: out[tok[m]] (+)= w[m] * (h[hbase+m] @ W2_e)
// expert_arg >= 0: fixed expert, hbase=0 (serialized fallback).
// expert_arg <  0: expert = blockIdx.z, hbase = offs[expert] (batched; accmode=1 -> atomicAdd).
// Tile 128x128, BK=64, 4 waves x (4x4) 16x16x32 bf16 MFMA.
// LDS: unpadded [128][64] (DMA lane order) with XOR chunk swizzle:
//   LDS slot (row, chunk c) holds global chunk c ^ (row&7); frag reads XOR the same.
template <int PHASE>
__global__ __launch_bounds__(256) void gemm_kernel(
    const unsigned short* __restrict__ A, const unsigned short* __restrict__ Wt,
    unsigned short* __restrict__ H, float* __restrict__ Out,
    const int* __restrict__ counts, const int* __restrict__ offs,
    const int* __restrict__ tok_list, const float* __restrict__ tok_w,
    int expert_arg, int accmode) {
  const int Kd = (PHASE == 1) ? DIM : INTER;
  int expert = (expert_arg >= 0) ? expert_arg : (int)blockIdx.z;
  int count = (expert < NEXP) ? counts[expert] : T_TOKENS;
  int m0 = blockIdx.y * 128;
  if (m0 >= count) return;
  int n0 = blockIdx.x * 128;
  int hbase = (expert_arg >= 0) ? 0 : ((expert < NEXP) ? offs[expert] : 2 * T_TOKENS);
  const unsigned short* Bt = Wt + (size_t)expert * (4096 * 1024);

  __shared__ __align__(16) unsigned short As[128 * 64];
  __shared__ __align__(16) unsigned short Bs[128 * 64];

  int tid = threadIdx.x;
  int wv = tid >> 6, lane = tid & 63;
  int lrow = lane >> 3;                       // 0..7 row within 8-row DMA stripe
  int lcol = ((lane & 7) ^ lrow) * 8;         // swizzled global chunk for this LDS slot

  const unsigned short* aG[4];
  const unsigned short* bG[4];
  unsigned short* aL[4];
  unsigned short* bL[4];
#pragma unroll
  for (int i = 0; i < 4; i++) {
    int r = wv * 32 + i * 8 + lrow;           // tile row 0..127
    int m = m0 + r;
    int src;
    if (PHASE == 1)
      src = (expert < NEXP) ? ((m < count) ? tok_list[expert * T_TOKENS + m] : 0) : m;
    else
      src = hbase + m;                         // h rows are bucket-ordered at hbase
    aG[i] = A + (size_t)src * Kd + lcol;
    bG[i] = Bt + (size_t)(n0 + r) * Kd + lcol;
    aL[i] = &As[(wv * 32 + i * 8) * 64];      // wave-uniform LDS base
    bL[i] = &Bs[(wv * 32 + i * 8) * 64];
  }

  f32x4 acc[4][4];
#pragma unroll
  for (int mf = 0; mf < 4; mf++)
#pragma unroll
    for (int nf = 0; nf < 4; nf++) acc[mf][nf] = (f32x4)0.f;

  int m_off = (wv & 1) * 64, n_off = (wv >> 1) * 64;
  int l15 = lane & 15, q = lane >> 4;
  int sw = l15 & 7;                            // frag-read swizzle (row&7 == l15&7)

  for (int k0 = 0; k0 < Kd; k0 += 64) {
#pragma unroll
    for (int i = 0; i < 4; i++) {
      load_lds16(aG[i], aL[i]);
      load_lds16(bG[i], bL[i]);
      aG[i] += 64; bG[i] += 64;
    }
    __syncthreads();   // drains DMA (vmcnt) + orders LDS
#pragma unroll
    for (int ks = 0; ks < 2; ks++) {
      int cofs = ((ks * 4 + q) ^ sw) * 8;      // swizzled chunk -> element offset
      bf16x8 af[4], bfr[4];
#pragma unroll
      for (int mf = 0; mf < 4; mf++)
        af[mf] = *(bf16x8*)&As[(m_off + mf * 16 + l15) * 64 + cofs];
#pragma unroll
      for (int nf = 0; nf < 4; nf++)
        bfr[nf] = *(bf16x8*)&Bs[(n_off + nf * 16 + l15) * 64 + cofs];
#pragma unroll
      for (int mf = 0; mf < 4; mf++)
#pragma unroll
        for (int nf = 0; nf < 4; nf++)
          acc[mf][nf] = __builtin_amdgcn_mfma_f32_16x16x32_bf16(af[mf], bfr[nf], acc[mf][nf], 0, 0, 0);
    }
    __syncthreads();
  }

  // C/D layout (m89-verified): col = lane&15, row = (lane>>4)*4 + i
  if (PHASE == 1) {
#pragma unroll
    for (int mf = 0; mf < 4; mf++)
#pragma unroll
      for (int i = 0; i < 4; i++) {
        int m = m0 + m_off + mf * 16 + q * 4 + i;
        if (m < count) {
#pragma unroll
          for (int nf = 0; nf < 4; nf++) {
            int f = n0 + n_off + nf * 16 + l15;
            float v = acc[mf][nf][i];
            H[(size_t)(hbase + m) * INTER + f] = f2b(v > 0.f ? v : 0.f);
          }
        }
      }
  } else {
#pragma unroll
    for (int mf = 0; mf < 4; mf++)
#pragma unroll
      for (int i = 0; i < 4; i++) {
        int m = m0 + m_off + mf * 16 + q * 4 + i;
        if (m < count) {
          int tokn; float swt;
          if (expert < NEXP) { tokn = tok_list[expert * T_TOKENS + m]; swt = tok_w[expert * T_TOKENS + m]; }
          else { tokn = m; swt = 1.f; }
          float* orow = Out + (size_t)tokn * DIM;
#pragma unroll
          for (int nf = 0; nf < 4; nf++) {
            int d = n0 + n_off + nf * 16 + l15;
            float v = swt * acc[mf][nf][i];
            if (accmode) atomicAdd(orow + d, v);          // batched: out pre-zeroed
            else if (expert < NEXP) orow[d] += v;          // serialized routed
            else orow[d] = v;                              // serialized shared (init)
          }
        }
      }
  }
}

extern "C" void kernel_launch(void* const* d_in, const int* in_sizes, int n_in,
                              void* d_out, int out_size, void* d_ws, size_t ws_size,
                              hipStream_t stream) {
  const float* x   = (const float*)d_in[0];
  const float* sw1 = (const float*)d_in[1];
  const float* sw2 = (const float*)d_in[2];
  const float* rw1 = (const float*)d_in[3];
  const float* rw2 = (const float*)d_in[4];
  const float* rtw = (const float*)d_in[5];
  float* out = (float*)d_out;

  char* ws = (char*)d_ws;
  unsigned short* xb  = (unsigned short*)(ws);
  unsigned short* w1t = (unsigned short*)(ws + 16777216);
  unsigned short* w2t = (unsigned short*)(ws + 92274688);
  unsigned short* h   = (unsigned short*)(ws + 167772160);
  // router scratch overlaid on head of h (consumed by bucket_kernel before h is written)
  int*   top_idx      = (int*)(ws + 167772160);
  float* top_w        = (float*)(ws + 167772160 + 32768);

  const size_t H_BIG  = (size_t)24576 * 4096 * 2;        // 201,326,592
  const size_t H_SMALL= (size_t)8192  * 4096 * 2;        //  67,108,864
  const size_t NEED_BIG = 167772160 + H_BIG + 262144 * 2 + 256;
  bool big = ws_size >= NEED_BIG;
  size_t tail = 167772160 + (big ? H_BIG : H_SMALL);
  int*   tok_list = (int*)(ws + tail);
  float* tok_w    = (float*)(ws + tail + 262144);
  int*   counts   = (int*)(ws + tail + 524288);
  int*   offs     = (int*)(ws + tail + 524288 + 64);

  cast_x_kernel<<<(T_TOKENS * DIM) / (256 * 4), 256, 0, stream>>>(x, xb);
  transpose_cast_kernel<<<dim3(128, 32, 9), 256, 0, stream>>>(rw1, sw1, w1t, 1024, 4096);
  transpose_cast_kernel<<<dim3(32, 128, 9), 256, 0, stream>>>(rw2, sw2, w2t, 4096, 1024);
  router_topk_kernel<<<T_TOKENS / 4, 256, 0, stream>>>(x, rtw, top_idx, top_w);
  bucket_kernel<<<1, 256, 0, stream>>>(top_idx, top_w, counts, offs, tok_list, tok_w);

  if (big) {
    hipMemsetAsync(out, 0, (size_t)T_TOKENS * DIM * sizeof(float), stream);
    // all 9 experts (z=8 is shared), one launch per phase; p2 accumulates atomically
    gemm_kernel<1><<<dim3(32, 64, 9), 256, 0, stream>>>(xb, w1t, h, nullptr,
                                                        counts, offs, tok_list, tok_w, -1, 1);
    gemm_kernel<2><<<dim3(8, 64, 9), 256, 0, stream>>>(h, w2t, nullptr, out,
                                                       counts, offs, tok_list, tok_w, -1, 1);
  } else {
    // serialized fallback: shared first (plain-store init), routed accumulate
    gemm_kernel<1><<<dim3(32, 64), 256, 0, stream>>>(xb, w1t, h, nullptr,
                                                     counts, offs, tok_list, tok_w, 8, 0);
    gemm_kernel<2><<<dim3(8, 64), 256, 0, stream>>>(h, w2t, nullptr, out,
                                                    counts, offs, tok_list, tok_w, 8, 0);
    for (int e = 0; e < 8; e++) {
      gemm_kernel<1><<<dim3(32, 64), 256, 0, stream>>>(xb, w1t, h, nullptr,
                                                       counts, offs, tok_list, tok_w, e, 0);
      gemm_kernel<2><<<dim3(8, 64), 256, 0, stream>>>(h, w2t, nullptr, out,
                                                      counts, offs, tok_list, tok_w, e, 0);
    }
  }
}